// Round 10
// baseline (176.267 us; speedup 1.0000x reference)
//
#include <hip/hip_runtime.h>
#include <stdint.h>

#define N_NODES 8192
#define IN_FEAT 512
#define OUT_FEAT 256
#define LOG2E 1.4426950408889634f

typedef __bf16 b16x8 __attribute__((ext_vector_type(8)));
typedef unsigned short u16x8v __attribute__((ext_vector_type(8)));
typedef float f32x4 __attribute__((ext_vector_type(4)));

static __device__ __forceinline__ unsigned short f2bf(float f) {
    union { float f; uint32_t u; } v; v.f = f;
    uint32_t r = v.u + 0x7FFFu + ((v.u >> 16) & 1u);
    return (unsigned short)(r >> 16);
}

// K0: Wt[c][k] = bf16(W[k][c])  (256 x 512)
__global__ __launch_bounds__(256) void k0_transpose_w(const float* __restrict__ W,
                                                      unsigned short* __restrict__ Wt) {
    int tid = blockIdx.x * 256 + threadIdx.x;
    int c = tid & (OUT_FEAT - 1);
    int k = tid >> 8;
    Wt[(size_t)c * IN_FEAT + k] = f2bf(W[(size_t)k * OUT_FEAT + c]);
}

// K1: h = X @ W via bf16 MFMA. Writes hTf in MFMA-B-fragment order.
__global__ __launch_bounds__(256) void k1_hgemm(const float* __restrict__ input,
                                                const unsigned short* __restrict__ Wt,
                                                const float* __restrict__ a_vec,
                                                unsigned short* __restrict__ hTf,
                                                float* __restrict__ s1_raw,
                                                float* __restrict__ s2_raw) {
    int tid = threadIdx.x;
    int lane = tid & 63;
    int c = lane & 15, g = lane >> 4;
    int r0 = blockIdx.x * 64 + (tid >> 6) * 16;
    f32x4 acc[16];
#pragma unroll
    for (int t = 0; t < 16; ++t) acc[t] = (f32x4){0.f, 0.f, 0.f, 0.f};
    const float* arow = input + (size_t)(r0 + c) * IN_FEAT;
#pragma unroll 1
    for (int kk = 0; kk < IN_FEAT / 32; ++kk) {
        int kb = kk * 32 + 8 * g;
        float4 x0 = *(const float4*)(arow + kb);
        float4 x1 = *(const float4*)(arow + kb + 4);
        u16x8v au;
        au[0] = f2bf(x0.x); au[1] = f2bf(x0.y); au[2] = f2bf(x0.z); au[3] = f2bf(x0.w);
        au[4] = f2bf(x1.x); au[5] = f2bf(x1.y); au[6] = f2bf(x1.z); au[7] = f2bf(x1.w);
        b16x8 af = __builtin_bit_cast(b16x8, au);
#pragma unroll
        for (int t = 0; t < 16; ++t) {
            b16x8 bf = __builtin_bit_cast(b16x8,
                *(const u16x8v*)(Wt + (size_t)(16 * t + c) * IN_FEAT + kb));
            acc[t] = __builtin_amdgcn_mfma_f32_16x16x32_bf16(af, bf, acc[t], 0, 0, 0);
        }
    }
    float a1v[16], a2v[16];
#pragma unroll
    for (int t = 0; t < 16; ++t) {
        a1v[t] = a_vec[16 * t + c];
        a2v[t] = a_vec[OUT_FEAT + 16 * t + c];
    }
#pragma unroll
    for (int r = 0; r < 4; ++r) {
        float s1p = 0.f, s2p = 0.f;
#pragma unroll
        for (int t = 0; t < 16; ++t) { s1p += acc[t][r] * a1v[t]; s2p += acc[t][r] * a2v[t]; }
#pragma unroll
        for (int m = 1; m <= 8; m <<= 1) { s1p += __shfl_xor(s1p, m); s2p += __shfl_xor(s2p, m); }
        if (c == 0) {
            int row = r0 + 4 * g + r;
            s1_raw[row] = s1p;
            s2_raw[row] = s2p;
        }
    }
    int chunk = r0 >> 5;
    int lp = ((r0 & 16) >> 3) + (g >> 1);
    int e0 = 4 * (g & 1);
#pragma unroll
    for (int t = 0; t < 16; ++t) {
        ushort4 pk;
        pk.x = f2bf(acc[t][0]); pk.y = f2bf(acc[t][1]);
        pk.z = f2bf(acc[t][2]); pk.w = f2bf(acc[t][3]);
        *(ushort4*)(hTf + ((size_t)(chunk * 16 + t) * 64 + lp * 16 + c) * 8 + e0) = pk;
    }
}

// K2: factored-exp constants.
// row2[i] = (E1r, E2r) = (exp2(K(s1-mi)), exp2(K(0.2*s1-mi)))
// e12[2j],e12[2j+1] = (exp2(K*s2_j), exp2(K*0.2*s2_j))
__global__ __launch_bounds__(256) void k2_prep(const float* __restrict__ s1_raw,
                                               const float* __restrict__ s2_raw,
                                               float* __restrict__ e12,
                                               float2* __restrict__ row2) {
    __shared__ float red[256];
    int tid = threadIdx.x;
    float m = -3.0e38f;
    for (int j = tid; j < N_NODES; j += 256) m = fmaxf(m, s2_raw[j]);
    red[tid] = m;
    __syncthreads();
    for (int s = 128; s > 0; s >>= 1) {
        if (tid < s) red[tid] = fmaxf(red[tid], red[tid + s]);
        __syncthreads();
    }
    float M2 = red[0];
    int i = blockIdx.x * 256 + tid;
    float s1 = s1_raw[i];
    float u = s1 + M2;
    float mi = fmaxf(u, 0.2f * u);                 // per-row upper bound on e (monotone LReLU)
    row2[i] = make_float2(__builtin_amdgcn_exp2f((s1 - mi) * LOG2E),
                          __builtin_amdgcn_exp2f((0.2f * s1 - mi) * LOG2E));
    float s2 = s2_raw[i];
    e12[2 * i]     = __builtin_amdgcn_exp2f(s2 * LOG2E);
    e12[2 * i + 1] = __builtin_amdgcn_exp2f(0.2f * s2 * LOG2E);
}

// K3 v9: depth-2 pipelined fused pack+flash-GAT.
// Grid 512 = 128 rowgroups (64 rows) x 4 jq. 4 waves: (rq 0..1) x (ch 0..1),
// wave owns 32 rows (dual A-frag) x 128 cols.
// 3-ring tiles/masks: at iter kk stage tile kk+2 (gll) + pack mask kk+2 (from
// adj regs loaded at kk-1) + issue adj kk+3; consume tile/mask kk.
// Steady state: ONE s_waitcnt vmcnt(6) after MFMAs (retires adj[kk+2] and tile
// kk+1), lgkmcnt(0)+s_barrier; gll/adj remain in flight ACROSS barriers.
// Score uses factored exp: p = max(E1r*e1c, E2r*e2c) — no transcendentals.
__global__ __launch_bounds__(256, 2) void k3_flash(const int* __restrict__ adj,
                                                   const unsigned short* __restrict__ hTf,
                                                   const float* __restrict__ e12g,
                                                   const float2* __restrict__ row2,
                                                   float* __restrict__ pout,
                                                   float* __restrict__ rowpart) {
    __shared__ __align__(16) unsigned short tiles[3][8192];  // 48 KB
    __shared__ uint32_t lmaskD[3][64];                       // 768 B
    __shared__ __align__(16) float le12[4096];               // 16 KB (e1c,e2c interleaved)

    int tid = threadIdx.x;
    int w = tid >> 6, lane = tid & 63;
    int c = lane & 15, g = lane >> 4;
    int ch = w & 1, rq = w >> 1;
    int jq = blockIdx.x & 3;
    int rg = blockIdx.x >> 2;
    int rowbase = rg * 64 + rq * 32;

    int mrow = tid >> 2;          // block-local row 0..63
    int mg8 = tid & 3;            // byte within dword
    const int* adjbase = adj + (size_t)(rg * 64 + mrow) * N_NODES + jq * 2048 + mg8 * 8;

#define PACK_TO(BUF, V0, V1)                                                             \
    {                                                                                    \
        unsigned b = (unsigned)((V0).x != 0) | ((unsigned)((V0).y != 0) << 1)            \
                   | ((unsigned)((V0).z != 0) << 2) | ((unsigned)((V0).w != 0) << 3)     \
                   | ((unsigned)((V1).x != 0) << 4) | ((unsigned)((V1).y != 0) << 5)     \
                   | ((unsigned)((V1).z != 0) << 6) | ((unsigned)((V1).w != 0) << 7);    \
        ((unsigned char*)&lmaskD[BUF][mrow])[mg8] = (unsigned char)b;                    \
    }

    // ---- prologue ----
    float2 rc0 = row2[rowbase + c];
    float2 rc1 = row2[rowbase + 16 + c];
    float E1r0 = rc0.x, E2r0 = rc0.y;
    float E1r1 = rc1.x, E2r1 = rc1.y;
    // e12 quarter -> LDS (16 floats/thread)
#pragma unroll
    for (int q = 0; q < 4; ++q) {
        *(float4*)&le12[tid * 16 + q * 4] =
            *(const float4*)(e12g + (size_t)jq * 4096 + tid * 16 + q * 4);
    }
    {   // masks for chunks 0,1 (synchronous)
        int4 v0 = *(const int4*)(adjbase);
        int4 v1 = *(const int4*)(adjbase + 4);
        int4 v2 = *(const int4*)(adjbase + 32);
        int4 v3 = *(const int4*)(adjbase + 36);
        PACK_TO(0, v0, v1)
        PACK_TO(1, v2, v3)
    }
    __builtin_amdgcn_sched_barrier(0);
    // gll tiles 0,1
#pragma unroll
    for (int b = 0; b < 2; ++b) {
        size_t jc = (size_t)(jq * 64 + b) * 8192;
#pragma unroll
        for (int q = 0; q < 4; ++q) {
            int ti = w * 4 + q;
            const unsigned short* src = hTf + jc + (size_t)(ti * 64 + lane) * 8;
            __builtin_amdgcn_global_load_lds(
                (const __attribute__((address_space(1))) uint32_t*)src,
                (__attribute__((address_space(3))) uint32_t*)(&tiles[b][ti * 512]), 16, 0, 0);
        }
    }
    __builtin_amdgcn_sched_barrier(0);
    // adj chunk 2 in-flight
    int4 va0 = *(const int4*)(adjbase + 64);
    int4 va1 = *(const int4*)(adjbase + 68);
    __builtin_amdgcn_sched_barrier(0);
    asm volatile("s_waitcnt vmcnt(2)" ::: "memory");       // tiles 0,1 done; adj2 in flight
    asm volatile("s_waitcnt lgkmcnt(0)" ::: "memory");
    __builtin_amdgcn_sched_barrier(0);
    __builtin_amdgcn_s_barrier();
    __builtin_amdgcn_sched_barrier(0);

    f32x4 acc0[8], acc1[8];
#pragma unroll
    for (int t = 0; t < 8; ++t) { acc0[t] = (f32x4){0,0,0,0}; acc1[t] = (f32x4){0,0,0,0}; }
    float lacc0 = 0.f, lacc1 = 0.f;

#define SCORE_AND_MFMA(CUR, KK)                                                          \
    {                                                                                    \
        uint32_t md0 = lmaskD[CUR][rq * 32 + c];                                         \
        uint32_t md1 = lmaskD[CUR][rq * 32 + 16 + c];                                    \
        uint32_t mb0 = (md0 >> (8 * g)) & 0xFFu;                                         \
        uint32_t mb1 = (md1 >> (8 * g)) & 0xFFu;                                         \
        float ev[16];                                                                    \
        _Pragma("unroll")                                                                \
        for (int q = 0; q < 4; ++q)                                                      \
            *(f32x4*)&ev[q * 4] = *(const f32x4*)&le12[((KK) * 32 + 8 * g) * 2 + q * 4]; \
        b16x8 af0, af1;                                                                  \
        _Pragma("unroll")                                                                \
        for (int e = 0; e < 8; ++e) {                                                    \
            float e1 = ev[2 * e], e2 = ev[2 * e + 1];                                    \
            float q0 = fmaxf(E1r0 * e1, E2r0 * e2);                                      \
            float p0 = (mb0 & (1u << e)) ? q0 : 0.f;                                     \
            lacc0 += p0;                                                                 \
            af0[e] = (__bf16)p0;                                                         \
            float q1 = fmaxf(E1r1 * e1, E2r1 * e2);                                      \
            float p1 = (mb1 & (1u << e)) ? q1 : 0.f;                                     \
            lacc1 += p1;                                                                 \
            af1[e] = (__bf16)p1;                                                         \
        }                                                                                \
        const unsigned short* tb = &tiles[CUR][ch * 8 * 512];                            \
        _Pragma("unroll")                                                                \
        for (int t = 0; t < 8; ++t) {                                                    \
            b16x8 bf = __builtin_bit_cast(b16x8, *(const u16x8v*)(tb + t * 512 + lane * 8)); \
            acc0[t] = __builtin_amdgcn_mfma_f32_16x16x32_bf16(af0, bf, acc0[t], 0, 0, 0); \
            acc1[t] = __builtin_amdgcn_mfma_f32_16x16x32_bf16(af1, bf, acc1[t], 0, 0, 0); \
        }                                                                                \
    }

    int cur = 0;          // kk % 3
    int nx2 = 2;          // (kk+2) % 3
#pragma unroll 1
    for (int kk = 0; kk < 61; ++kk) {
        // stage tile kk+2 -> tiles[nx2]
        {
            size_t jc = (size_t)(jq * 64 + kk + 2) * 8192;
#pragma unroll
            for (int q = 0; q < 4; ++q) {
                int ti = w * 4 + q;
                const unsigned short* src = hTf + jc + (size_t)(ti * 64 + lane) * 8;
                __builtin_amdgcn_global_load_lds(
                    (const __attribute__((address_space(1))) uint32_t*)src,
                    (__attribute__((address_space(3))) uint32_t*)(&tiles[nx2][ti * 512]), 16, 0, 0);
            }
        }
        __builtin_amdgcn_sched_barrier(0);
        // adj chunk kk+3
        int4 vb0 = *(const int4*)(adjbase + (kk + 3) * 32);
        int4 vb1 = *(const int4*)(adjbase + (kk + 3) * 32 + 4);
        __builtin_amdgcn_sched_barrier(0);
        // compute chunk kk
        SCORE_AND_MFMA(cur, kk)
        __builtin_amdgcn_sched_barrier(0);
        // retire adj[kk+2] (and tile kk+1); keep tile kk+2 + adj kk+3 in flight
        asm volatile("s_waitcnt vmcnt(6)" ::: "memory");
        __builtin_amdgcn_sched_barrier(0);
        PACK_TO(nx2, va0, va1)
        va0 = vb0; va1 = vb1;
        __builtin_amdgcn_sched_barrier(0);
        asm volatile("s_waitcnt lgkmcnt(0)" ::: "memory");
        __builtin_amdgcn_sched_barrier(0);
        __builtin_amdgcn_s_barrier();
        __builtin_amdgcn_sched_barrier(0);
        cur = (cur == 2) ? 0 : cur + 1;
        nx2 = (nx2 == 2) ? 0 : nx2 + 1;
    }
    // kk = 61 (cur=1, nx2=0): stage tile 63, no adj issue, pack chunk 63
    {
        size_t jc = (size_t)(jq * 64 + 63) * 8192;
#pragma unroll
        for (int q = 0; q < 4; ++q) {
            int ti = w * 4 + q;
            const unsigned short* src = hTf + jc + (size_t)(ti * 64 + lane) * 8;
            __builtin_amdgcn_global_load_lds(
                (const __attribute__((address_space(1))) uint32_t*)src,
                (__attribute__((address_space(3))) uint32_t*)(&tiles[0][ti * 512]), 16, 0, 0);
        }
        __builtin_amdgcn_sched_barrier(0);
        SCORE_AND_MFMA(1, 61)
        __builtin_amdgcn_sched_barrier(0);
        asm volatile("s_waitcnt vmcnt(4)" ::: "memory");   // retire adj[63] + tile 62
        __builtin_amdgcn_sched_barrier(0);
        PACK_TO(0, va0, va1)
        __builtin_amdgcn_sched_barrier(0);
        asm volatile("s_waitcnt lgkmcnt(0)" ::: "memory");
        __builtin_amdgcn_sched_barrier(0);
        __builtin_amdgcn_s_barrier();
        __builtin_amdgcn_sched_barrier(0);
    }
    // kk = 62 (cur=2): compute only; drain tile 63 before barrier
    {
        SCORE_AND_MFMA(2, 62)
        __builtin_amdgcn_sched_barrier(0);
        asm volatile("s_waitcnt vmcnt(0)" ::: "memory");
        asm volatile("s_waitcnt lgkmcnt(0)" ::: "memory");
        __builtin_amdgcn_sched_barrier(0);
        __builtin_amdgcn_s_barrier();
        __builtin_amdgcn_sched_barrier(0);
    }
    // kk = 63 (cur=0)
    SCORE_AND_MFMA(0, 63)

    // partial row sums over this j-quarter
    float l0 = lacc0 + __shfl_xor(lacc0, 16); l0 += __shfl_xor(l0, 32);
    float l1 = lacc1 + __shfl_xor(lacc1, 16); l1 += __shfl_xor(l1, 32);
    if (ch == 0 && g == 0) {
        rowpart[jq * N_NODES + rowbase + c] = l0;
        rowpart[jq * N_NODES + rowbase + 16 + c] = l1;
    }

#pragma unroll
    for (int r = 0; r < 4; ++r) {
        int grow0 = rowbase + 4 * g + r;        // C layout: row=(lane>>4)*4+reg
        int grow1 = grow0 + 16;
#pragma unroll
        for (int t = 0; t < 8; ++t) {
            pout[((size_t)jq * N_NODES + grow0) * OUT_FEAT + ch * 128 + 16 * t + c] = acc0[t][r];
            pout[((size_t)jq * N_NODES + grow1) * OUT_FEAT + ch * 128 + 16 * t + c] = acc1[t][r];
        }
    }
#undef SCORE_AND_MFMA
#undef PACK_TO
}

// K4: out = elu( (sum_q pout[q]) / (sum_q rowpart[q]) ).
__global__ __launch_bounds__(256) void k4_reduce(const float* __restrict__ pout,
                                                 const float* __restrict__ rowpart,
                                                 float* __restrict__ out) {
    int t = blockIdx.x * 256 + threadIdx.x;
    int row = t >> 8;
    float s = 0.f, l = 0.f;
#pragma unroll
    for (int q = 0; q < 4; ++q) {
        s += pout[(size_t)q * N_NODES * OUT_FEAT + t];
        l += rowpart[q * N_NODES + row];
    }
    float inv = (l > 0.f) ? 1.0f / l : 0.f;
    float x = s * inv;
    out[t] = (x > 0.f) ? x : (__builtin_amdgcn_exp2f(x * LOG2E) - 1.0f);
}

extern "C" void kernel_launch(void* const* d_in, const int* in_sizes, int n_in,
                              void* d_out, int out_size, void* d_ws, size_t ws_size,
                              hipStream_t stream) {
    const float* input = (const float*)d_in[0];
    const int* adj = (const int*)d_in[1];
    const float* W = (const float*)d_in[2];
    const float* a_vec = (const float*)d_in[3];
    float* out = (float*)d_out;

    char* ws = (char*)d_ws;
    unsigned short* Wt  = (unsigned short*)(ws);                 // 256 KB
    unsigned short* hTf = (unsigned short*)(ws + 262144);        // 4 MB
    float*  e12     = (float*)(ws + 4456448);                    // 64 KB
    float2* row2    = (float2*)(ws + 4521984);                   // 64 KB
    float*  s1_raw  = (float*)(ws + 4587520);                    // 32 KB
    float*  s2_raw  = (float*)(ws + 4620288);                    // 32 KB
    float*  rowpart = (float*)(ws + 13008896);                   // 128 KB
    float*  pout    = (float*)(ws + 13139968);                   // 32 MB

    hipLaunchKernelGGL(k0_transpose_w, dim3(512), dim3(256), 0, stream, W, Wt);
    hipLaunchKernelGGL(k1_hgemm, dim3(N_NODES / 64), dim3(256), 0, stream,
                       input, Wt, a_vec, hTf, s1_raw, s2_raw);
    hipLaunchKernelGGL(k2_prep, dim3(32), dim3(256), 0, stream, s1_raw, s2_raw, e12, row2);
    hipLaunchKernelGGL(k3_flash, dim3(512), dim3(256), 0, stream,
                       adj, hTf, e12, row2, pout, rowpart);
    hipLaunchKernelGGL(k4_reduce, dim3(N_NODES * OUT_FEAT / 256), dim3(256), 0, stream,
                       pout, rowpart, out);
}